// Round 3
// baseline (243.764 us; speedup 1.0000x reference)
//
#include <hip/hip_runtime.h>

typedef __attribute__((ext_vector_type(8))) short short8;
typedef __attribute__((ext_vector_type(4))) float float4v;
typedef __attribute__((ext_vector_type(4))) unsigned short us4;

#define DIN 128
#define NROWS 65536
#define SSIZE 1024
#define MLGK 256
#define DOUT 10
#define TM 64   // rows per block; 4 waves x 16 rows, waves fully independent

__device__ inline unsigned short f2bf(float f) {
  unsigned int u = __float_as_uint(f);
  u = (u + 0x7FFFu + ((u >> 16) & 1u)) >> 16;
  return (unsigned short)u;
}
__device__ inline float bf2f(unsigned short h) {
  return __uint_as_float(((unsigned int)h) << 16);
}
// mish(x) = x*tanh(softplus(x)) = x*((1+e^x)^2-1)/((1+e^x)^2+1)
__device__ inline float mish_f(float x) {
  if (x > 30.f) return x;
  float e = __expf(x);
  float u = 1.f + e;
  float u2 = u * u;
  return x * (u2 - 1.f) / (u2 + 1.f);
}
// LDS element-index swizzle: breaks the D=128 row-major bank conflict (G4)
__device__ inline int swz(int row, int col) {
  return row * DIN + (col ^ ((row & 7) << 3));
}

// ---------- tiny precompute kernels (all fp32 math, negligible cost) ----------

__global__ __launch_bounds__(256) void k_prep(const float* __restrict__ W1,
                                              const float* __restrict__ W2,
                                              const float* __restrict__ Wc,
                                              unsigned short* W1b, unsigned short* W2b,
                                              unsigned short* Wcb) {
  int i = blockIdx.x * 256 + threadIdx.x;  // 49152 total
  if (i < 16384) {
    W1b[i] = f2bf(W1[i]);
  } else if (i < 32768) {
    W2b[i - 16384] = f2bf(W2[i - 16384]);
  } else {
    int j = i - 32768;              // [16][1024] padded Wc (rows >= DOUT are zero)
    int o = j >> 10;
    int s = j & 1023;
    Wcb[j] = (o < DOUT) ? f2bf(Wc[o * SSIZE + s]) : (unsigned short)0;
  }
}

__global__ __launch_bounds__(256) void k_anchor_tanh(const float* __restrict__ Wa,
                                                     const float* __restrict__ mlg,
                                                     float* anc_raw) {
  int i = blockIdx.x * 256 + threadIdx.x;  // 1024*128
  int s = i >> 7, d = i & 127;
  float acc = 0.f;
  for (int k = 0; k < MLGK; ++k) acc += Wa[s * MLGK + k] * mlg[k * DIN + d];
  anc_raw[i] = tanhf(acc);
}

__global__ __launch_bounds__(256) void k_encode(const float* __restrict__ in,
                                                const float* __restrict__ W,
                                                const float* __restrict__ b,
                                                float* out_f32, unsigned short* out_bf16) {
  int i = blockIdx.x * 256 + threadIdx.x;  // rows*128
  int r = i >> 7, d = i & 127;
  float acc = 0.f;
  for (int k = 0; k < DIN; ++k) acc += in[r * DIN + k] * W[d * DIN + k];
  float m = mish_f(acc + b[d]);
  if (out_f32) out_f32[i] = m;
  if (out_bf16) out_bf16[i] = f2bf(m);
}

__global__ __launch_bounds__(256) void k_a2(const unsigned short* __restrict__ ancb,
                                            float* a2) {
  int s = blockIdx.x * 256 + threadIdx.x;
  if (s >= SSIZE) return;
  float acc = 0.f;
  for (int d = 0; d < DIN; ++d) {
    float v = bf2f(ancb[s * DIN + d]);
    acc += v * v;
  }
  a2[s] = acc;
}

// ---------- the fused main kernel ----------
// 4 independent waves per block, 16 x-rows each. NO __syncthreads anywhere.
// Layer1 loads x global->reg; h/x_dml live in a wave-private LDS region
// (in-place). Distance MFMA computes dist^T (A=anchors, B=x_dml) so the C-tile
// feeds the logits MFMA directly as a zero-padded B-fragment (k-slot placement
// consistent between A and B => any HW k-permutation cancels). Logits stay in
// registers; log_softmax via 2 shfl_xor; no barriers at all.

__global__ __launch_bounds__(256, 4) void k_main(
    const float* __restrict__ x, const float* __restrict__ b1,
    const float* __restrict__ b2, const float* __restrict__ bc,
    const unsigned short* __restrict__ W1b, const unsigned short* __restrict__ W2b,
    const unsigned short* __restrict__ Wcb, const unsigned short* __restrict__ ancb,
    const float* __restrict__ a2, float* __restrict__ out) {
  __shared__ __align__(16) unsigned short ldsA[TM * DIN];  // h, then x_dml (wave-private rows)
  __shared__ float x2s[TM];

  const int tid = threadIdx.x;
  const int wid = tid >> 6;        // wave owns rows [wid*16, wid*16+16)
  const int lane = tid & 63;
  const int l15 = lane & 15;
  const int lhi = lane >> 4;
  const int n0 = blockIdx.x * TM;
  const int rbase = wid * 16;

  // ---- layer 1: A-fragments (x rows) straight from global, f32->bf16 ----
  short8 af[4];
#pragma unroll
  for (int kk = 0; kk < 4; ++kk) {
    const float* p = x + (size_t)(n0 + rbase + l15) * DIN + kk * 32 + lhi * 8;
    float4 u = *(const float4*)p;
    float4 v = *(const float4*)(p + 4);
    short8 a;
    a[0] = f2bf(u.x); a[1] = f2bf(u.y); a[2] = f2bf(u.z); a[3] = f2bf(u.w);
    a[4] = f2bf(v.x); a[5] = f2bf(v.y); a[6] = f2bf(v.z); a[7] = f2bf(v.w);
    af[kk] = a;
  }

  // ---- encode layers (wave-private; dst rows == wave's own rows) ----
  // layer==0: A from af[] regs, write h to ldsA. layer==1: A from ldsA (h),
  // write x_dml to ldsA in-place, plus row-norm x2.
#pragma unroll 1
  for (int layer = 0; layer < 2; ++layer) {
    const unsigned short* Wb = layer ? W2b : W1b;
    const float* bias = layer ? b2 : b1;
    float4v acc[8];
#pragma unroll
    for (int ct = 0; ct < 8; ++ct) acc[ct] = (float4v){0.f, 0.f, 0.f, 0.f};
#pragma unroll
    for (int kk = 0; kk < 4; ++kk) {
      int k = kk * 32 + lhi * 8;
      short8 a = layer ? *(const short8*)&ldsA[swz(rbase + l15, k)] : af[kk];
#pragma unroll
      for (int ct = 0; ct < 8; ++ct) {
        short8 b = *(const short8*)&Wb[(ct * 16 + l15) * DIN + k];
        acc[ct] = __builtin_amdgcn_mfma_f32_16x16x32_bf16(a, b, acc[ct], 0, 0, 0);
      }
    }
    float sq[4] = {0.f, 0.f, 0.f, 0.f};
#pragma unroll
    for (int ct = 0; ct < 8; ++ct) {
      int col = ct * 16 + l15;
      float bv = bias[col];
#pragma unroll
      for (int j = 0; j < 4; ++j) {
        float m = mish_f(acc[ct][j] + bv);
        unsigned short mb = f2bf(m);
        if (layer) {
          float mf = bf2f(mb);
          sq[j] += mf * mf;
        }
        ldsA[swz(rbase + lhi * 4 + j, col)] = mb;
      }
    }
    if (layer) {
#pragma unroll
      for (int j = 0; j < 4; ++j) {
        float s = sq[j];
        s += __shfl_xor(s, 1, 16);
        s += __shfl_xor(s, 2, 16);
        s += __shfl_xor(s, 4, 16);
        s += __shfl_xor(s, 8, 16);
        if (l15 == 0) x2s[rbase + lhi * 4 + j] = s;
      }
    }
  }

  // ---- hoist x_dml B-fragments (wave's 16 rows) and this lane's x2 ----
  short8 bx[4];
#pragma unroll
  for (int kk = 0; kk < 4; ++kk)
    bx[kk] = *(const short8*)&ldsA[swz(rbase + l15, kk * 32 + lhi * 8)];
  const float x2v = x2s[rbase + l15];

  // ---- distance (dist^T) + in-register logits over 8 anchor tiles ----
  float4v lacc = (float4v){0.f, 0.f, 0.f, 0.f};

#pragma unroll 1
  for (int st = 0; st < 8; ++st) {
    float4v acc[8];
#pragma unroll
    for (int ct = 0; ct < 8; ++ct) acc[ct] = (float4v){0.f, 0.f, 0.f, 0.f};

#pragma unroll
    for (int kk = 0; kk < 4; ++kk) {
      int k = kk * 32 + lhi * 8;
#pragma unroll
      for (int ct = 0; ct < 8; ++ct) {
        int sg = st * 128 + ct * 16 + l15;        // anchor row (A operand, m-dim)
        short8 a = *(const short8*)&ancb[sg * DIN + k];
        acc[ct] = __builtin_amdgcn_mfma_f32_16x16x32_bf16(a, bx[kk], acc[ct], 0, 0, 0);
      }
    }
    // lane holds dot[s = st*128+ct*16+lhi*4+j][xrow = rbase+l15]
#pragma unroll
    for (int ct = 0; ct < 8; ++ct) {
      int sb = st * 128 + ct * 16 + lhi * 4;
      float4 av = *(const float4*)&a2[sb];
      unsigned short db[4];
#pragma unroll
      for (int j = 0; j < 4; ++j) {
        float sqv = x2v + (&av.x)[j] - 2.f * acc[ct][j];
        db[j] = f2bf(sqrtf(fmaxf(sqv, 0.f)));
      }
      // logits^T += Wc_frag (A, zero-padded) * dist_frag (B, zero-padded)
      us4 w4 = *(const us4*)&Wcb[l15 * SSIZE + sb];
      short8 a8 = {(short)w4[0], (short)w4[1], (short)w4[2], (short)w4[3], 0, 0, 0, 0};
      short8 b8 = {(short)db[0], (short)db[1], (short)db[2], (short)db[3], 0, 0, 0, 0};
      lacc = __builtin_amdgcn_mfma_f32_16x16x32_bf16(a8, b8, lacc, 0, 0, 0);
    }
  }

  // ---- bias + log_softmax + store ----
  // lane holds logits[o = lhi*4+j][xrow = rbase+l15]
  {
    const int xrow = n0 + rbase + l15;
    float v[4];
    float m4 = -1e30f;
#pragma unroll
    for (int j = 0; j < 4; ++j) {
      int o = lhi * 4 + j;
      bool valid = o < DOUT;
      v[j] = valid ? (lacc[j] + bc[o]) : -1e30f;
      m4 = fmaxf(m4, v[j]);
    }
    m4 = fmaxf(m4, __shfl_xor(m4, 16));
    m4 = fmaxf(m4, __shfl_xor(m4, 32));
    float es = 0.f;
    float ev[4];
#pragma unroll
    for (int j = 0; j < 4; ++j) {
      int o = lhi * 4 + j;
      ev[j] = (o < DOUT) ? __expf(v[j] - m4) : 0.f;
      es += ev[j];
    }
    es += __shfl_xor(es, 16);
    es += __shfl_xor(es, 32);
    float ls = logf(es);
#pragma unroll
    for (int j = 0; j < 4; ++j) {
      int o = lhi * 4 + j;
      if (o < DOUT) out[(size_t)xrow * DOUT + o] = v[j] - m4 - ls;
    }
  }
}

extern "C" void kernel_launch(void* const* d_in, const int* in_sizes, int n_in,
                              void* d_out, int out_size, void* d_ws, size_t ws_size,
                              hipStream_t stream) {
  const float* x   = (const float*)d_in[0];
  const float* mlg = (const float*)d_in[1];
  const float* W1  = (const float*)d_in[2];
  const float* b1  = (const float*)d_in[3];
  const float* W2  = (const float*)d_in[4];
  const float* b2  = (const float*)d_in[5];
  const float* Wa  = (const float*)d_in[6];
  const float* Wc  = (const float*)d_in[7];
  const float* bc  = (const float*)d_in[8];
  float* out = (float*)d_out;

  // workspace layout (~1.41 MB total)
  unsigned short* W1b  = (unsigned short*)d_ws;        // 16384 bf16
  unsigned short* W2b  = W1b + 16384;                  // 16384 bf16
  unsigned short* Wcb  = W2b + 16384;                  // 16*1024 bf16 (zero-padded)
  unsigned short* ancb = Wcb + 16384;                  // 1024*128 bf16
  float* a2      = (float*)(ancb + SSIZE * DIN);       // 1024 f32
  float* anc_raw = a2 + SSIZE;                         // 1024*128 f32
  float* anc_h   = anc_raw + SSIZE * DIN;              // 1024*128 f32

  k_prep<<<192, 256, 0, stream>>>(W1, W2, Wc, W1b, W2b, Wcb);
  k_anchor_tanh<<<512, 256, 0, stream>>>(Wa, mlg, anc_raw);
  k_encode<<<512, 256, 0, stream>>>(anc_raw, W1, b1, anc_h, nullptr);
  k_encode<<<512, 256, 0, stream>>>(anc_h, W2, b2, nullptr, ancb);
  k_a2<<<4, 256, 0, stream>>>(ancb, a2);
  k_main<<<1024, 256, 0, stream>>>(x, b1, b2, bc, W1b, W2b, Wcb, ancb, a2, out);
}

// Round 4
// 117.533 us; speedup vs baseline: 2.0740x; 2.0740x over previous
//
#include <hip/hip_runtime.h>

typedef __attribute__((ext_vector_type(8))) short short8;
typedef __attribute__((ext_vector_type(4))) float float4v;
typedef __attribute__((ext_vector_type(4))) unsigned short us4;
typedef __attribute__((address_space(3))) unsigned int as3u32;
typedef __attribute__((address_space(1))) unsigned int as1u32;

#define DIN 128
#define SSIZE 1024
#define MLGK 256
#define DOUT 10
#define TM 64   // x-rows per block; 4 waves x 16 rows
#define TS 64   // anchors per staged tile
#define NT 16   // anchor tiles

__device__ inline unsigned short f2bf(float f) {
  unsigned int u = __float_as_uint(f);
  u = (u + 0x7FFFu + ((u >> 16) & 1u)) >> 16;
  return (unsigned short)u;
}
__device__ inline float bf2f(unsigned short h) {
  return __uint_as_float(((unsigned int)h) << 16);
}
__device__ inline float mish_f(float x) {
  if (x > 30.f) return x;
  float e = __expf(x);
  float u = 1.f + e;
  float u2 = u * u;
  return x * (u2 - 1.f) / (u2 + 1.f);
}
// element-index XOR swizzle; identical to the chunk-XOR used by stage64
__device__ inline int swz(int row, int col) {
  return row * DIN + (col ^ ((row & 7) << 3));
}

// Stage a 64x128 bf16 tile (row stride DIN) into a 16KB LDS region via
// global_load_lds width=16. LDS dest is LINEAR in lane order (HW constraint,
// rule #21); the XOR swizzle is applied by permuting the GLOBAL source chunk.
__device__ inline void stage64(const unsigned short* __restrict__ gsrc,
                               unsigned short* region, int tid) {
#pragma unroll
  for (int it = 0; it < 4; ++it) {
    int slot = it * 256 + tid;
    int r = slot >> 4;
    int c8 = (slot & 15) ^ (r & 7);
    __builtin_amdgcn_global_load_lds((const as1u32*)(gsrc + r * DIN + c8 * 8),
                                     (as3u32*)(region + slot * 8), 16, 0, 0);
  }
}

// ---------- tiny precompute kernels ----------

__global__ __launch_bounds__(256) void k_prep(const float* __restrict__ W1,
                                              const float* __restrict__ W2,
                                              const float* __restrict__ Wc,
                                              unsigned short* W1b, unsigned short* W2b,
                                              unsigned short* Wcb) {
  int i = blockIdx.x * 256 + threadIdx.x;  // 49152 total
  if (i < 16384) {
    W1b[i] = f2bf(W1[i]);
  } else if (i < 32768) {
    W2b[i - 16384] = f2bf(W2[i - 16384]);
  } else {
    int j = i - 32768;  // [16][1024] padded Wc (rows >= DOUT are zero)
    int o = j >> 10;
    int s = j & 1023;
    Wcb[j] = (o < DOUT) ? f2bf(Wc[o * SSIZE + s]) : (unsigned short)0;
  }
}

__global__ __launch_bounds__(256) void k_anchor_tanh(const float* __restrict__ Wa,
                                                     const float* __restrict__ mlg,
                                                     float* anc_raw) {
  int i = blockIdx.x * 256 + threadIdx.x;  // 1024*128
  int s = i >> 7, d = i & 127;
  float acc = 0.f;
  for (int k = 0; k < MLGK; ++k) acc += Wa[s * MLGK + k] * mlg[k * DIN + d];
  anc_raw[i] = tanhf(acc);
}

__global__ __launch_bounds__(256) void k_encode(const float* __restrict__ in,
                                                const float* __restrict__ W,
                                                const float* __restrict__ b,
                                                float* out_f32, unsigned short* out_bf16) {
  int i = blockIdx.x * 256 + threadIdx.x;  // rows*128
  int r = i >> 7, d = i & 127;
  float acc = 0.f;
  for (int k = 0; k < DIN; ++k) acc += in[r * DIN + k] * W[d * DIN + k];
  float m = mish_f(acc + b[d]);
  if (out_f32) out_f32[i] = m;
  if (out_bf16) out_bf16[i] = f2bf(m);
}

__global__ __launch_bounds__(256) void k_a2(const unsigned short* __restrict__ ancb,
                                            float* a2) {
  int s = blockIdx.x * 256 + threadIdx.x;
  if (s >= SSIZE) return;
  float acc = 0.f;
  for (int d = 0; d < DIN; ++d) {
    float v = bf2f(ancb[s * DIN + d]);
    acc += v * v;
  }
  a2[s] = acc;
}

// ---------- fused main kernel ----------
// 4 waves x 16 x-rows. W and anchor tiles cooperatively staged into LDS
// (double-buffered, global_load_lds w=16, pre-swizzled source). Distance MFMA
// computes dist^T so the C tile feeds the logits MFMA directly (in-register);
// log_softmax via shfl. One barrier per staged tile.

__global__ __launch_bounds__(256, 4) void k_main(
    const float* __restrict__ x, const float* __restrict__ b1,
    const float* __restrict__ b2, const float* __restrict__ bc,
    const unsigned short* __restrict__ W1b, const unsigned short* __restrict__ W2b,
    const unsigned short* __restrict__ Wcb, const unsigned short* __restrict__ ancb,
    const float* __restrict__ a2, float* __restrict__ out) {
  __shared__ __align__(16) unsigned short reg0[TM * DIN];  // h/x_dml; then anchor buf A
  __shared__ __align__(16) unsigned short reg1[TM * DIN];  // W halves; then anchor buf B
  __shared__ __align__(16) float ldsa2[SSIZE];

  const int tid = threadIdx.x;
  const int wid = tid >> 6;
  const int lane = tid & 63;
  const int l15 = lane & 15;
  const int lhi = lane >> 4;
  const int n0 = blockIdx.x * TM;
  const int rbase = wid * 16;

  // a2 -> LDS (overlaps with first W stage)
  for (int i = tid; i < SSIZE; i += 256) ldsa2[i] = a2[i];

  // ---- x rows -> bf16 A-fragments (global -> reg) ----
  short8 af[4];
#pragma unroll
  for (int kk = 0; kk < 4; ++kk) {
    const float* p = x + (size_t)(n0 + rbase + l15) * DIN + kk * 32 + lhi * 8;
    float4 u = *(const float4*)p;
    float4 v = *(const float4*)(p + 4);
    short8 a;
    a[0] = f2bf(u.x); a[1] = f2bf(u.y); a[2] = f2bf(u.z); a[3] = f2bf(u.w);
    a[4] = f2bf(v.x); a[5] = f2bf(v.y); a[6] = f2bf(v.z); a[7] = f2bf(v.w);
    af[kk] = a;
  }

  // ---- encode: 2 layers x 2 staged 64-col halves of W ----
#pragma unroll 1
  for (int layer = 0; layer < 2; ++layer) {
    const unsigned short* Wb = layer ? W2b : W1b;
    const float* bias = layer ? b2 : b1;
    short8 ah[4];
#pragma unroll
    for (int kk = 0; kk < 4; ++kk)
      ah[kk] = layer ? *(const short8*)&reg0[swz(rbase + l15, kk * 32 + lhi * 8)]
                     : af[kk];
#pragma unroll 1
    for (int half = 0; half < 2; ++half) {
      stage64(Wb + (size_t)(half * 64) * DIN, reg1, tid);
      __syncthreads();  // W half staged (vmcnt drained by barrier)
      float4v acc[4];
#pragma unroll
      for (int ct = 0; ct < 4; ++ct) acc[ct] = (float4v){0.f, 0.f, 0.f, 0.f};
#pragma unroll
      for (int kk = 0; kk < 4; ++kk) {
        int k = kk * 32 + lhi * 8;
#pragma unroll
        for (int ct = 0; ct < 4; ++ct) {
          short8 b = *(const short8*)&reg1[swz(ct * 16 + l15, k)];
          acc[ct] = __builtin_amdgcn_mfma_f32_16x16x32_bf16(ah[kk], b, acc[ct], 0, 0, 0);
        }
      }
      __syncthreads();  // all waves done reading reg1 before next stage
#pragma unroll
      for (int ct = 0; ct < 4; ++ct) {
        int col = half * 64 + ct * 16 + l15;
        float bv = bias[col];
#pragma unroll
        for (int j = 0; j < 4; ++j) {
          float m = mish_f(acc[ct][j] + bv);
          reg0[swz(rbase + lhi * 4 + j, col)] = f2bf(m);  // wave-private rows
        }
      }
    }
  }

  // ---- hoist x_dml B-fragments; row norm from the rounded registers ----
  short8 bx[4];
#pragma unroll
  for (int kk = 0; kk < 4; ++kk)
    bx[kk] = *(const short8*)&reg0[swz(rbase + l15, kk * 32 + lhi * 8)];
  float x2v = 0.f;
#pragma unroll
  for (int kk = 0; kk < 4; ++kk)
#pragma unroll
    for (int e = 0; e < 8; ++e) {
      float v = bf2f((unsigned short)bx[kk][e]);
      x2v += v * v;
    }
  x2v += __shfl_xor(x2v, 16);
  x2v += __shfl_xor(x2v, 32);   // full row-norm of row rbase+l15
  __syncthreads();              // everyone done with reg0 before anchor staging

  // ---- distance + in-register logits over 16 anchor tiles of 64 ----
  float4v lacc[2];
  lacc[0] = (float4v){0.f, 0.f, 0.f, 0.f};
  lacc[1] = (float4v){0.f, 0.f, 0.f, 0.f};

  auto dist_tile = [&](const unsigned short* buf, int t) {
    float4v acc[4];
#pragma unroll
    for (int ct = 0; ct < 4; ++ct) acc[ct] = (float4v){0.f, 0.f, 0.f, 0.f};
#pragma unroll
    for (int kk = 0; kk < 4; ++kk) {
      int k = kk * 32 + lhi * 8;
#pragma unroll
      for (int ct = 0; ct < 4; ++ct) {
        short8 a = *(const short8*)&buf[swz(ct * 16 + l15, k)];
        acc[ct] = __builtin_amdgcn_mfma_f32_16x16x32_bf16(a, bx[kk], acc[ct], 0, 0, 0);
      }
    }
#pragma unroll
    for (int ct = 0; ct < 4; ++ct) {
      int sb = t * TS + ct * 16 + lhi * 4;
      float4 av = *(const float4*)&ldsa2[sb];
      us4 w4 = *(const us4*)&Wcb[l15 * SSIZE + sb];
      unsigned short db[4];
#pragma unroll
      for (int j = 0; j < 4; ++j) {
        float sqv = fmaf(-2.f, acc[ct][j], x2v + (&av.x)[j]);
        db[j] = f2bf(sqrtf(fmaxf(sqv, 0.f)));
      }
      short8 a8 = {(short)w4[0], (short)w4[1], (short)w4[2], (short)w4[3], 0, 0, 0, 0};
      short8 b8 = {(short)db[0], (short)db[1], (short)db[2], (short)db[3], 0, 0, 0, 0};
      lacc[ct & 1] = __builtin_amdgcn_mfma_f32_16x16x32_bf16(a8, b8, lacc[ct & 1], 0, 0, 0);
    }
  };

  stage64(ancb, reg0, tid);  // tile 0
  __syncthreads();
#pragma unroll 1
  for (int tp = 0; tp < NT / 2; ++tp) {
    stage64(ancb + (size_t)(2 * tp + 1) * TS * DIN, reg1, tid);  // in flight over compute
    dist_tile(reg0, 2 * tp);
    __syncthreads();
    if (tp < NT / 2 - 1)
      stage64(ancb + (size_t)(2 * tp + 2) * TS * DIN, reg0, tid);
    dist_tile(reg1, 2 * tp + 1);
    __syncthreads();
  }
  float4v L = lacc[0] + lacc[1];

  // ---- bias + log_softmax + store (lane holds logits[lhi*4+j][row l15]) ----
  {
    const int xrow = n0 + rbase + l15;
    float v[4];
    float m4 = -1e30f;
#pragma unroll
    for (int j = 0; j < 4; ++j) {
      int o = lhi * 4 + j;
      v[j] = (o < DOUT) ? (L[j] + bc[o]) : -1e30f;
      m4 = fmaxf(m4, v[j]);
    }
    m4 = fmaxf(m4, __shfl_xor(m4, 16));
    m4 = fmaxf(m4, __shfl_xor(m4, 32));
    float es = 0.f;
#pragma unroll
    for (int j = 0; j < 4; ++j) {
      int o = lhi * 4 + j;
      es += (o < DOUT) ? __expf(v[j] - m4) : 0.f;
    }
    es += __shfl_xor(es, 16);
    es += __shfl_xor(es, 32);
    float ls = logf(es);
#pragma unroll
    for (int j = 0; j < 4; ++j) {
      int o = lhi * 4 + j;
      if (o < DOUT) out[(size_t)xrow * DOUT + o] = v[j] - m4 - ls;
    }
  }
}

extern "C" void kernel_launch(void* const* d_in, const int* in_sizes, int n_in,
                              void* d_out, int out_size, void* d_ws, size_t ws_size,
                              hipStream_t stream) {
  const float* x   = (const float*)d_in[0];
  const float* mlg = (const float*)d_in[1];
  const float* W1  = (const float*)d_in[2];
  const float* b1  = (const float*)d_in[3];
  const float* W2  = (const float*)d_in[4];
  const float* b2  = (const float*)d_in[5];
  const float* Wa  = (const float*)d_in[6];
  const float* Wc  = (const float*)d_in[7];
  const float* bc  = (const float*)d_in[8];
  float* out = (float*)d_out;

  // workspace layout (~1.41 MB total)
  unsigned short* W1b  = (unsigned short*)d_ws;        // 16384 bf16
  unsigned short* W2b  = W1b + 16384;                  // 16384 bf16
  unsigned short* Wcb  = W2b + 16384;                  // 16*1024 bf16 (zero-padded)
  unsigned short* ancb = Wcb + 16384;                  // 1024*128 bf16
  float* a2      = (float*)(ancb + SSIZE * DIN);       // 1024 f32
  float* anc_raw = a2 + SSIZE;                         // 1024*128 f32
  float* anc_h   = anc_raw + SSIZE * DIN;              // 1024*128 f32

  k_prep<<<192, 256, 0, stream>>>(W1, W2, Wc, W1b, W2b, Wcb);
  k_anchor_tanh<<<512, 256, 0, stream>>>(Wa, mlg, anc_raw);
  k_encode<<<512, 256, 0, stream>>>(anc_raw, W1, b1, anc_h, nullptr);
  k_encode<<<512, 256, 0, stream>>>(anc_h, W2, b2, nullptr, ancb);
  k_a2<<<4, 256, 0, stream>>>(ancb, a2);
  k_main<<<1024, 256, 0, stream>>>(x, b1, b2, bc, W1b, W2b, Wcb, ancb, a2, out);
}